// Round 3
// baseline (607.723 us; speedup 1.0000x reference)
//
#include <hip/hip_runtime.h>
#include <hip/hip_bf16.h>
#include <cstdint>
#include <cstddef>

// ---------- types ----------
typedef __bf16 bf16x8 __attribute__((ext_vector_type(8)));
typedef float  f32x4  __attribute__((ext_vector_type(4)));

#define VOC   50000
#define TPW   4        // trees per workgroup (compose kernel)
#define XSTR  72       // LDS row stride in bf16 elems (padded, 16B-aligned rows)

// ---------- static device scratch (no ws_size dependency) ----------
__device__ int g_isbf16;                                            // 1 = tensors stored bf16, 0 = float32
__device__ __attribute__((aligned(256))) unsigned short g_vocT[(size_t)VOC * 64];
__device__ __attribute__((aligned(256))) unsigned short g_roots[2048 * 64];
__device__ __attribute__((aligned(256))) unsigned short g_cpst_w[64 * 4096];
__device__ __attribute__((aligned(256))) unsigned short g_cprt_w[64 * 4096];
__device__ __attribute__((aligned(256))) unsigned short g_cps_w[64 * 128];
__device__ __attribute__((aligned(256))) unsigned short g_cpr_w[64 * 128];
__device__ float g_smw[7 * 64];
__device__ float g_smb[7];
__device__ float g_biasC[64];   // cps_b + cpst_b
__device__ float g_biasF[64];   // cpr_b + cprt_b

__device__ __forceinline__ float b2f(unsigned short u) {
    unsigned int x = ((unsigned int)u) << 16;
    return __builtin_bit_cast(float, x);
}
__device__ __forceinline__ unsigned short f2b(float f) {
    return __builtin_bit_cast(unsigned short, (__bf16)f);   // RNE convert
}
__device__ __forceinline__ float scrub(float v) {           // NaN->finite, cheap insurance
    return fminf(fmaxf(v, -64.f), 64.f);
}
__device__ __forceinline__ float ldf(const void* p, size_t i, int isb) {
    return isb ? b2f(((const unsigned short*)p)[i]) : ((const float*)p)[i];
}

// ---------- kernel 0: detect storage dtype from voc_b ----------
__global__ void k_detect(const void* __restrict__ voc_b) {
    if (threadIdx.x == 0 && blockIdx.x == 0) {
        const unsigned int* p = (const unsigned int*)voc_b;
        int ok = 1;
        for (int k = 0; k < 32; k++) {
            unsigned short lo = (unsigned short)(p[k] & 0xFFFFu);
            float v = b2f(lo);
            if (!(fabsf(v) <= 0.0502f)) ok = 0;   // NaN fails -> f32
        }
        g_isbf16 = ok;
    }
}

// ---------- kernel 0b: canonicalize weights/biases ----------
__global__ __launch_bounds__(256) void k_convert(
    const void* cps_w, const void* cps_b, const void* cpst_w, const void* cpst_b,
    const void* cpr_w, const void* cpr_b, const void* cprt_w, const void* cprt_b,
    const void* sm_w, const void* sm_b)
{
    const int isb = g_isbf16;
    int gid = blockIdx.x * 256 + threadIdx.x;
    int stride = gridDim.x * 256;
    for (int i = gid; i < 64 * 4096; i += stride) g_cpst_w[i] = f2b(ldf(cpst_w, i, isb));
    for (int i = gid; i < 64 * 4096; i += stride) g_cprt_w[i] = f2b(ldf(cprt_w, i, isb));
    for (int i = gid; i < 64 * 128;  i += stride) g_cps_w[i]  = f2b(ldf(cps_w,  i, isb));
    for (int i = gid; i < 64 * 128;  i += stride) g_cpr_w[i]  = f2b(ldf(cpr_w,  i, isb));
    for (int i = gid; i < 448;       i += stride) g_smw[i]    = ldf(sm_w, i, isb);
    if (gid < 64) {
        g_biasC[gid] = ldf(cps_b, gid, isb) + ldf(cpst_b, gid, isb);
        g_biasF[gid] = ldf(cpr_b, gid, isb) + ldf(cprt_b, gid, isb);
    }
    if (gid < 7) g_smb[gid] = ldf(sm_b, gid, isb);
}

// ---------- kernel 1: voc_w (64 x 50000) -> g_vocT[50000][64] bf16, fold voc_b ----------
__global__ __launch_bounds__(256) void k_vocT(const void* __restrict__ voc_w,
                                              const void* __restrict__ voc_b) {
    __shared__ float tile[64][65];
    __shared__ float vb[64];
    const int isb = g_isbf16;
    int t = threadIdx.x;
    if (t < 64) vb[t] = ldf(voc_b, t, isb);
    int v0 = blockIdx.x * 64;
    int vl = t & 63, dr = t >> 6;
    #pragma unroll
    for (int i = 0; i < 16; i++) {
        int d = dr * 16 + i;
        int v = v0 + vl;
        tile[vl][d] = (v < VOC) ? ldf(voc_w, (size_t)d * VOC + v, isb) : 0.f;  // coalesced along v
    }
    __syncthreads();
    int dl = t & 63, vr0 = t >> 6;
    #pragma unroll
    for (int i = 0; i < 16; i++) {
        int vr = vr0 * 16 + i;
        int v = v0 + vr;
        if (v < VOC) g_vocT[(size_t)v * 64 + dl] = f2b(tile[vr][dl] + vb[dl]); // coalesced along d
    }
}

// ---------- kernel 2: compose both trees bottom-up; 4 trees per WG, levels in LDS ----------
__global__ __launch_bounds__(256) void k_compose(
    const int* __restrict__ lleaf, const int* __restrict__ rleaf)
{
    __shared__ unsigned short X[256 * XSTR];   // 256 node slots x 64 dims (bf16, padded)
    __shared__ float biasC[64];
    const int tid = threadIdx.x;
    const int wg  = blockIdx.x;
    if (tid < 64) biasC[tid] = g_biasC[tid];

    // ---- leaf embedding load: slot l = t*64 + leaf_i ----
    {
        int l = tid;                 // 0..255
        int t = l >> 6, i = l & 63;
        int g = wg * TPW + t;        // tree id: 0..1023 left, 1024..2047 right
        int b = (g < 1024) ? g : g - 1024;
        const int* lv = (g < 1024) ? lleaf : rleaf;
        int idx = lv[b * 64 + i];
        idx = (idx < 0) ? 0 : ((idx >= VOC) ? VOC - 1 : idx);
        const int4* src = (const int4*)(g_vocT + (size_t)idx * 64);
        int4* dst = (int4*)(X + l * XSTR);          // l*144 bytes: 16B aligned
        #pragma unroll
        for (int z = 0; z < 8; z++) dst[z] = src[z];
    }
    __syncthreads();

    const int lane = tid & 63, wave = tid >> 6;
    const int q = lane >> 4, sub = lane & 15;

    // ---- levels: new node (t,n) <- old (t,2n),(t,2n+1) ----
    for (int lg = 5; lg >= 0; lg--) {
        const int c_new = 1 << lg;
        const int nodes = TPW << lg;              // 128,64,32,16,8,4
        const int nchunks = (nodes + 15) >> 4;    // 8,4,2,1,1,1

        f32x4 acc[2][4];
        #pragma unroll
        for (int ci = 0; ci < 2; ci++)
            #pragma unroll
            for (int nt = 0; nt < 4; nt++)
                #pragma unroll
                for (int z = 0; z < 4; z++) acc[ci][nt][z] = 0.f;

        int chs[2];  int act[2];
        #pragma unroll
        for (int ci = 0; ci < 2; ci++) { chs[ci] = wave + ci * 4; act[ci] = (chs[ci] < nchunks); }
        const bool any = act[0] || act[1];

        int slotL[2], slotR[2];
        #pragma unroll
        for (int ci = 0; ci < 2; ci++) {
            int m = chs[ci] * 16 + sub; if (m >= nodes) m = 0;   // clamp padded rows
            int t = m >> lg, n = m & (c_new - 1);
            slotL[ci] = t * 64 + 2 * n; slotR[ci] = slotL[ci] + 1;
        }

        if (any) {
            for (int kb = 0; kb < 132; kb++) {     // K = 4096 (kron) + 128 (concat)
                bf16x8 bfr[4];
                {
                    const unsigned short* Bb; int bstr, boff;
                    if (kb < 128) { Bb = g_cpst_w; bstr = 4096; boff = kb * 32 + q * 8; }
                    else          { Bb = g_cps_w;  bstr = 128;  boff = (kb - 128) * 32 + q * 8; }
                    #pragma unroll
                    for (int nt = 0; nt < 4; nt++)
                        bfr[nt] = *(const bf16x8*)(Bb + (nt * 16 + sub) * bstr + boff);
                }
                #pragma unroll
                for (int ci = 0; ci < 2; ci++) {
                    if (!act[ci]) continue;
                    bf16x8 afr;
                    if (kb < 128) {                       // kron: A = L[i]*L[j] (ref uses L⊗L)
                        int i  = kb >> 1;
                        int j0 = (kb & 1) * 32 + q * 8;
                        float Li = b2f(X[slotL[ci] * XSTR + i]);
                        bf16x8 rv = *(const bf16x8*)(X + slotL[ci] * XSTR + j0);
                        #pragma unroll
                        for (int z = 0; z < 8; z++) afr[z] = (__bf16)((float)rv[z] * Li);
                    } else {                              // concat(L,R)
                        int kc = (kb - 128) * 32 + q * 8;
                        afr = (kc < 64) ? *(const bf16x8*)(X + slotL[ci] * XSTR + kc)
                                        : *(const bf16x8*)(X + slotR[ci] * XSTR + (kc - 64));
                    }
                    #pragma unroll
                    for (int nt = 0; nt < 4; nt++)
                        acc[ci][nt] = __builtin_amdgcn_mfma_f32_16x16x32_bf16(afr, bfr[nt], acc[ci][nt], 0, 0, 0);
                }
            }
        }
        __syncthreads();   // all reads of old level done before any in-place write
        if (any) {
            #pragma unroll
            for (int ci = 0; ci < 2; ci++) {
                if (!act[ci]) continue;
                #pragma unroll
                for (int nt = 0; nt < 4; nt++) {
                    int e = nt * 16 + sub;                // C col = lane&15
                    #pragma unroll
                    for (int r = 0; r < 4; r++) {
                        int m = chs[ci] * 16 + q * 4 + r; // C row = quad*4 + reg
                        if (m < nodes) {
                            float v = tanhf(scrub(acc[ci][nt][r] + biasC[e]));
                            int t = m >> lg, n = m & (c_new - 1);
                            X[(t * 64 + n) * XSTR + e] = f2b(v);
                        }
                    }
                }
            }
        }
        __syncthreads();
    }

    // ---- roots ----
    {
        int t = tid >> 6, d = tid & 63;
        int g = wg * TPW + t;
        g_roots[(size_t)g * 64 + d] = X[(t * 64) * XSTR + d];
    }
}

// ---------- kernel 3: final cpr/cprt + leaky_relu + softmax ----------
__global__ __launch_bounds__(256) void k_final(void* __restrict__ out)
{
    __shared__ unsigned short Lv[64 * XSTR], Rv[64 * XSTR];
    __shared__ float actS[64][65];
    __shared__ float smw[7][64];
    __shared__ float smbS[7];
    __shared__ float biasF[64];
    const int tid = threadIdx.x, wg = blockIdx.x;
    const int isb = g_isbf16;
    if (tid < 64) biasF[tid] = g_biasF[tid];
    if (tid < 7)  smbS[tid] = g_smb[tid];
    for (int z = tid; z < 448; z += 256) smw[z >> 6][z & 63] = g_smw[z];

    {   // load l and r roots for 64 batch items
        int row = tid >> 1, half = tid & 1;      // 128 rows x 2 halves (32 bf16 each)
        int item = row & 63; bool isR = row >= 64;
        const unsigned short* src = g_roots + (size_t)((isR ? 1024 : 0) + wg * 64 + item) * 64 + half * 32;
        unsigned short* dst = (isR ? Rv : Lv) + item * XSTR + half * 32;
        const int4* s4 = (const int4*)src; int4* d4 = (int4*)dst;
        #pragma unroll
        for (int z = 0; z < 4; z++) d4[z] = s4[z];
    }
    __syncthreads();

    const int lane = tid & 63, wave = tid >> 6;
    const int q = lane >> 4, sub = lane & 15;
    const int item = wave * 16 + sub;            // A row (batch item within WG)

    f32x4 acc[4];
    #pragma unroll
    for (int nt = 0; nt < 4; nt++)
        #pragma unroll
        for (int z = 0; z < 4; z++) acc[nt][z] = 0.f;

    for (int kb = 0; kb < 132; kb++) {
        bf16x8 bfr[4];
        const unsigned short* Bb; int bstr, boff;
        if (kb < 128) { Bb = g_cprt_w; bstr = 4096; boff = kb * 32 + q * 8; }
        else          { Bb = g_cpr_w;  bstr = 128;  boff = (kb - 128) * 32 + q * 8; }
        #pragma unroll
        for (int nt = 0; nt < 4; nt++)
            bfr[nt] = *(const bf16x8*)(Bb + (nt * 16 + sub) * bstr + boff);

        bf16x8 afr;
        if (kb < 128) {                          // kron = l[i] * r[j]
            int i = kb >> 1, j0 = (kb & 1) * 32 + q * 8;
            float Li = b2f(Lv[item * XSTR + i]);
            bf16x8 rv = *(const bf16x8*)(Rv + item * XSTR + j0);
            #pragma unroll
            for (int z = 0; z < 8; z++) afr[z] = (__bf16)((float)rv[z] * Li);
        } else {                                 // concat(l, r)
            int kc = (kb - 128) * 32 + q * 8;
            afr = (kc < 64) ? *(const bf16x8*)(Lv + item * XSTR + kc)
                            : *(const bf16x8*)(Rv + item * XSTR + (kc - 64));
        }
        #pragma unroll
        for (int nt = 0; nt < 4; nt++)
            acc[nt] = __builtin_amdgcn_mfma_f32_16x16x32_bf16(afr, bfr[nt], acc[nt], 0, 0, 0);
    }

    // epilogue: bias + leaky_relu -> LDS
    #pragma unroll
    for (int nt = 0; nt < 4; nt++) {
        int e = nt * 16 + sub;
        #pragma unroll
        for (int r = 0; r < 4; r++) {
            int it = wave * 16 + q * 4 + r;
            float v = scrub(acc[nt][r] + biasF[e]);
            v = (v > 0.f) ? v : 0.01f * v;
            actS[it][e] = v;
        }
    }
    __syncthreads();

    if (tid < 64) {                              // per-item 7x64 matvec + softmax
        float lg[7];
        #pragma unroll
        for (int j = 0; j < 7; j++) lg[j] = smbS[j];
        for (int e = 0; e < 64; e++) {
            float a = actS[tid][e];
            #pragma unroll
            for (int j = 0; j < 7; j++) lg[j] += smw[j][e] * a;
        }
        float mx = lg[0];
        #pragma unroll
        for (int j = 1; j < 7; j++) mx = fmaxf(mx, lg[j]);
        float s = 0.f, p[7];
        #pragma unroll
        for (int j = 0; j < 7; j++) { p[j] = expf(lg[j] - mx); s += p[j]; }
        float inv = 1.f / s;
        size_t b = (size_t)wg * 64 + tid;
        if (isb) {
            unsigned short* o = (unsigned short*)out;
            #pragma unroll
            for (int j = 0; j < 7; j++) o[b * 7 + j] = f2b(p[j] * inv);
        } else {
            float* o = (float*)out;
            #pragma unroll
            for (int j = 0; j < 7; j++) o[b * 7 + j] = p[j] * inv;
        }
    }
}

// ---------- host launcher ----------
extern "C" void kernel_launch(void* const* d_in, const int* in_sizes, int n_in,
                              void* d_out, int out_size, void* d_ws, size_t ws_size,
                              hipStream_t stream) {
    const int* lleaf = (const int*)d_in[0];
    const int* rleaf = (const int*)d_in[1];
    const void* voc_w  = d_in[2];
    const void* voc_b  = d_in[3];
    const void* cps_w  = d_in[4];
    const void* cps_b  = d_in[5];
    const void* cpst_w = d_in[6];
    const void* cpst_b = d_in[7];
    const void* cpr_w  = d_in[8];
    const void* cpr_b  = d_in[9];
    const void* cprt_w = d_in[10];
    const void* cprt_b = d_in[11];
    const void* sm_w   = d_in[12];
    const void* sm_b   = d_in[13];

    k_detect<<<1, 64, 0, stream>>>(voc_b);
    k_convert<<<512, 256, 0, stream>>>(cps_w, cps_b, cpst_w, cpst_b,
                                       cpr_w, cpr_b, cprt_w, cprt_b, sm_w, sm_b);
    k_vocT<<<(VOC + 63) / 64, 256, 0, stream>>>(voc_w, voc_b);
    k_compose<<<2048 / TPW, 256, 0, stream>>>(lleaf, rleaf);
    k_final<<<1024 / 64, 256, 0, stream>>>(d_out);
}